// Round 4
// baseline (1355.075 us; speedup 1.0000x reference)
//
#include <hip/hip_runtime.h>

typedef __attribute__((ext_vector_type(8))) short short8;
typedef __attribute__((ext_vector_type(4))) float f32x4;

#define C_DIM 512
#define KSTEP 64
#define ROW_BYTES 144            // 64 bf16 = 128B + 16B pad (2-way max bank aliasing)
#define B_OFF 9216               // A region: 64 * 144
#define GEMM_BYTES 46080         // 9216 + 256*144
#define PARTS 4

// round-to-nearest-even fp32 -> bf16 bits (no NaN in this workload)
__device__ __forceinline__ short f2bf(float f) {
  unsigned u = __float_as_uint(f);
  unsigned r = (u + 0x7fff + ((u >> 16) & 1)) >> 16;
  return (short)r;
}

// Combined prep: w_t[a][k] = bf16(w1|w2 [k][a]) for a in [0,256), k in [0,512);
// plus idx normalization to int32 on the first S global threads.
// idx values are in [1, N], N < 2^31: little-endian int64 input has odd 32-bit
// words all zero; int32 input has p32[1] = idx[1] >= 1. Detection exact here.
__global__ __launch_bounds__(256) void prep(const float* __restrict__ w1,
                                            const float* __restrict__ w2,
                                            short* __restrict__ w_t,
                                            const int* __restrict__ idx_raw,
                                            int* __restrict__ idx32, int S) {
  int t = blockIdx.x * 256 + threadIdx.x;   // 131072 total
  int a = t >> 9;
  int k = t & 511;
  float v = (a < 128) ? w1[k * 128 + a] : w2[k * 128 + (a - 128)];
  w_t[a * 512 + k] = f2bf(v);
  if (t < S) {
    bool is64 = (idx_raw[1] == 0) && (idx_raw[3] == 0);
    idx32[t] = is64 ? idx_raw[2 * t] : idx_raw[t];
  }
}

// ---------------------------------------------------------------------------
// FUSED path: one block per (segment, part). Part p handles tiles p, p+4, ...
// of its segment. Per tile: bf16 MFMA GEMM -> 64 scores -> online-softmax
// update of (m, d) and fp32 pooled accumulator; pooling re-reads the tile
// from cache. Partials merged by merge_mlp.
// ---------------------------------------------------------------------------
__global__ __launch_bounds__(256) void seg_part(
    const float* __restrict__ x, const short* __restrict__ w_t,
    const float* __restrict__ b1, const float* __restrict__ b2,
    const float* __restrict__ w_score, const float* __restrict__ b_score,
    const int* __restrict__ idx32,
    float* __restrict__ part_m, float* __restrict__ part_d,
    float* __restrict__ part_acc) {
  __shared__ __align__(16) char smem[GEMM_BYTES];
  __shared__ float wrow[64];
  __shared__ float m_sh, d_sh, scale_sh;

  const int bid = blockIdx.x;
  const int s = bid >> 2;          // PARTS = 4
  const int p = bid & 3;
  const int tid = threadIdx.x;
  const int w = tid >> 6;          // wave id
  const int lane = tid & 63;
  const int lo = lane & 15;
  const int hi = lane >> 4;
  const int sr = tid >> 2;         // A-staging row 0..63
  const int sq = tid & 3;          // 16-float chunk

  const int start = (s == 0) ? 0 : idx32[s - 1];
  const int end = idx32[s];
  const int T = (end - start + 63) >> 6;

  if (tid == 0) { m_sh = -INFINITY; d_sh = 0.f; }
  __syncthreads();

  float accp0 = 0.f, accp1 = 0.f;   // pooled accumulator, cols {2*tid, 2*tid+1}
  const int c0 = tid * 2;
  const float bsc = b_score[0];

  for (int t = p; t < T; t += PARTS) {
    const int row0 = start + t * 64;
    const int rv = min(64, end - row0);

    f32x4 acc[4][4];
#pragma unroll
    for (int i = 0; i < 4; ++i)
#pragma unroll
      for (int j = 0; j < 4; ++j) acc[i][j] = (f32x4)0.f;

    for (int st = 0; st < 8; ++st) {
      const int kk0 = st * KSTEP;
      // ---- stage A tile: 64 rows x 64 k, fp32 -> bf16 (rows >= end zeroed)
      {
        char* dst = smem + sr * ROW_BYTES + sq * 32;
        if (row0 + sr < end) {
          const float4* src = reinterpret_cast<const float4*>(
              x + (size_t)(row0 + sr) * C_DIM + kk0 + sq * 16);
          float4 f0 = src[0], f1 = src[1], f2 = src[2], f3 = src[3];
          short8 v0, v1;
          v0[0] = f2bf(f0.x); v0[1] = f2bf(f0.y); v0[2] = f2bf(f0.z); v0[3] = f2bf(f0.w);
          v0[4] = f2bf(f1.x); v0[5] = f2bf(f1.y); v0[6] = f2bf(f1.z); v0[7] = f2bf(f1.w);
          v1[0] = f2bf(f2.x); v1[1] = f2bf(f2.y); v1[2] = f2bf(f2.z); v1[3] = f2bf(f2.w);
          v1[4] = f2bf(f3.x); v1[5] = f2bf(f3.y); v1[6] = f2bf(f3.z); v1[7] = f2bf(f3.w);
          *reinterpret_cast<short8*>(dst) = v0;
          *reinterpret_cast<short8*>(dst + 16) = v1;
        } else {
          short8 z = (short8)0;
          *reinterpret_cast<short8*>(dst) = z;
          *reinterpret_cast<short8*>(dst + 16) = z;
        }
      }
      // ---- stage B tile: 256 cols x 64 k (bf16, from L2-resident w_t)
#pragma unroll
      for (int i = 0; i < 8; ++i) {
        int c = i * 256 + tid;
        int col = c >> 3;
        int part = c & 7;
        short8 v = *reinterpret_cast<const short8*>(w_t + col * 512 + kk0 + part * 8);
        *reinterpret_cast<short8*>(smem + B_OFF + col * ROW_BYTES + part * 16) = v;
      }
      __syncthreads();
      // ---- MFMA: 2 k-subslices of 32
#pragma unroll
      for (int ks = 0; ks < 2; ++ks) {
        short8 af[4], bf[4];
#pragma unroll
        for (int rg = 0; rg < 4; ++rg)
          af[rg] = *reinterpret_cast<const short8*>(
              smem + (rg * 16 + lo) * ROW_BYTES + ks * 64 + hi * 16);
#pragma unroll
        for (int cg = 0; cg < 4; ++cg)
          bf[cg] = *reinterpret_cast<const short8*>(
              smem + B_OFF + (w * 64 + cg * 16 + lo) * ROW_BYTES + ks * 64 + hi * 16);
#pragma unroll
        for (int rg = 0; rg < 4; ++rg)
#pragma unroll
          for (int cg = 0; cg < 4; ++cg)
            acc[rg][cg] = __builtin_amdgcn_mfma_f32_16x16x32_bf16(
                af[rg], bf[cg], acc[rg][cg], 0, 0, 0);
      }
      __syncthreads();
    }

    // ---- epilogue: srow = sum_a tanh(v_a+b1)*sigmoid(u_a+b2)*w_score[a]
    // C/D layout (verified m89): col = lane&15, row = (lane>>4)*4 + j
    float* U = reinterpret_cast<float*>(smem + B_OFF);  // [64][132] sig(u)*wsc
    float* sp = reinterpret_cast<float*>(smem);         // [64][2] partial sums

    if (w >= 2) {   // u-half (GEMM cols 128..255)
#pragma unroll
      for (int cg = 0; cg < 4; ++cg) {
        int a = (w - 2) * 64 + cg * 16 + lo;
        float bb = b2[a];
        float wsc = w_score[a];
#pragma unroll
        for (int rg = 0; rg < 4; ++rg)
#pragma unroll
          for (int j = 0; j < 4; ++j) {
            float v = acc[rg][cg][j] + bb;
            float sg = 1.f / (1.f + __expf(-v));
            U[(rg * 16 + hi * 4 + j) * 132 + a] = sg * wsc;
          }
      }
    }
    __syncthreads();
    if (w < 2) {    // v-half (GEMM cols 0..127)
#pragma unroll
      for (int rg = 0; rg < 4; ++rg) {
        float sacc[4] = {0.f, 0.f, 0.f, 0.f};
#pragma unroll
        for (int cg = 0; cg < 4; ++cg) {
          int a = w * 64 + cg * 16 + lo;
          float bb = b1[a];
#pragma unroll
          for (int j = 0; j < 4; ++j) {
            float v = acc[rg][cg][j] + bb;
            float e2 = __expf(2.f * v);
            float th = 1.f - 2.f / (e2 + 1.f);
            sacc[j] += th * U[(rg * 16 + hi * 4 + j) * 132 + a];
          }
        }
#pragma unroll
        for (int j = 0; j < 4; ++j) {
          float v = sacc[j];
          v += __shfl_xor(v, 1); v += __shfl_xor(v, 2);
          v += __shfl_xor(v, 4); v += __shfl_xor(v, 8);
          if (lo == 0) sp[(rg * 16 + hi * 4 + j) * 2 + w] = v;
        }
      }
    }
    __syncthreads();

    // ---- online-softmax stats for this tile (wave 0)
    if (tid < 64) {
      float sraw = sp[tid * 2] + sp[tid * 2 + 1] + bsc;
      float sv = (tid < rv) ? sraw : -INFINITY;
      float v = sv;
#pragma unroll
      for (int off = 1; off < 64; off <<= 1) v = fmaxf(v, __shfl_xor(v, off));
      const float m_old = m_sh;
      const float m_new = fmaxf(m_old, v);   // finite: rv >= 1
      float we = __expf(sv - m_new);         // -inf -> 0
      wrow[tid] = we;
#pragma unroll
      for (int off = 1; off < 64; off <<= 1) we += __shfl_xor(we, off);
      if (tid == 0) {
        float scl = __expf(m_old - m_new);   // -inf -> 0 on first tile
        d_sh = d_sh * scl + we;
        scale_sh = scl;
        m_sh = m_new;
      }
    }
    __syncthreads();

    // ---- pooling: rescale + accumulate this tile (rows re-read from cache)
    {
      const float scl = scale_sh;
      accp0 *= scl;
      accp1 *= scl;
      const float* xp = x + (size_t)row0 * C_DIM + c0;
#pragma unroll 4
      for (int j = 0; j < rv; ++j) {
        const float wv = wrow[j];
        const float2 xv = *reinterpret_cast<const float2*>(xp + (size_t)j * C_DIM);
        accp0 = fmaf(wv, xv.x, accp0);
        accp1 = fmaf(wv, xv.y, accp1);
      }
    }
    __syncthreads();   // protect smem/wrow before next tile's staging
  }

  part_acc[(size_t)bid * C_DIM + c0] = accp0;
  part_acc[(size_t)bid * C_DIM + c0 + 1] = accp1;
  if (tid == 0) { part_m[bid] = m_sh; part_d[bid] = d_sh; }
}

// Merge the PARTS partials of each segment, then MLP head.
__global__ __launch_bounds__(256) void merge_mlp(
    const float* __restrict__ part_m, const float* __restrict__ part_d,
    const float* __restrict__ part_acc,
    const float* __restrict__ w_m1, const float* __restrict__ b_m1,
    const float* __restrict__ w_m2, const float* __restrict__ b_m2,
    float* __restrict__ out) {
  const int s = blockIdx.x;
  const int tid = threadIdx.x;
  __shared__ float pooled[512];
  __shared__ float hpart[4][64];

  float mp[PARTS], dp[PARTS];
  float M = -INFINITY;
#pragma unroll
  for (int p = 0; p < PARTS; ++p) {
    mp[p] = part_m[s * PARTS + p];
    dp[p] = part_d[s * PARTS + p];
    M = fmaxf(M, mp[p]);
  }
  float wp[PARTS];
  float D = 0.f;
#pragma unroll
  for (int p = 0; p < PARTS; ++p) {
    wp[p] = (mp[p] > -INFINITY) ? __expf(mp[p] - M) : 0.f;
    D += dp[p] * wp[p];
  }
  const float inv = (D > 0.f) ? 1.f / D : 0.f;

  const int c0 = tid * 2;
  float a0 = 0.f, a1 = 0.f;
#pragma unroll
  for (int p = 0; p < PARTS; ++p) {
    const size_t base = (size_t)(s * PARTS + p) * C_DIM;
    a0 = fmaf(part_acc[base + c0], wp[p], a0);
    a1 = fmaf(part_acc[base + c0 + 1], wp[p], a1);
  }
  pooled[c0] = a0 * inv;
  pooled[c0 + 1] = a1 * inv;
  __syncthreads();

  // MLP: h = relu(pooled @ w_m1 + b_m1); out = relu(h @ w_m2 + b_m2)
  const int o = tid & 63, part = tid >> 6;
  float hs = 0.f;
#pragma unroll 8
  for (int c = part * 128; c < part * 128 + 128; ++c)
    hs = fmaf(pooled[c], w_m1[c * 64 + o], hs);
  hpart[part][o] = hs;
  __syncthreads();
  if (tid < 64) {
    float hv = fmaxf(hpart[0][tid] + hpart[1][tid] + hpart[2][tid] + hpart[3][tid]
                     + b_m1[tid], 0.f);
    float pr = hv * w_m2[tid];
#pragma unroll
    for (int off = 1; off < 64; off <<= 1) pr += __shfl_xor(pr, off);
    if (tid == 0) out[s] = fmaxf(pr + b_m2[0], 0.f);
  }
}

// ---------------------------------------------------------------------------
// FALLBACK path (used only if ws_size can't hold the fused partials):
// previous audited two-pass pipeline.
// ---------------------------------------------------------------------------
__global__ __launch_bounds__(256) void score_kernel(
    const float* __restrict__ x, const short* __restrict__ w_t,
    const float* __restrict__ b1, const float* __restrict__ b2,
    const float* __restrict__ w_score, const float* __restrict__ b_score,
    float* __restrict__ score) {
  __shared__ __align__(16) char smem[GEMM_BYTES];
  const int tid = threadIdx.x;
  const int w = tid >> 6;
  const int lane = tid & 63;
  const int lo = lane & 15;
  const int hi = lane >> 4;
  const int row0 = blockIdx.x * 64;

  f32x4 acc[4][4];
#pragma unroll
  for (int i = 0; i < 4; ++i)
#pragma unroll
    for (int j = 0; j < 4; ++j) acc[i][j] = (f32x4)0.f;

  const int sr = tid >> 2;
  const int sq = tid & 3;

  for (int st = 0; st < 8; ++st) {
    const int kk0 = st * KSTEP;
    {
      const float4* src = reinterpret_cast<const float4*>(
          x + (size_t)(row0 + sr) * C_DIM + kk0 + sq * 16);
      float4 f0 = src[0], f1 = src[1], f2 = src[2], f3 = src[3];
      short8 v0, v1;
      v0[0] = f2bf(f0.x); v0[1] = f2bf(f0.y); v0[2] = f2bf(f0.z); v0[3] = f2bf(f0.w);
      v0[4] = f2bf(f1.x); v0[5] = f2bf(f1.y); v0[6] = f2bf(f1.z); v0[7] = f2bf(f1.w);
      v1[0] = f2bf(f2.x); v1[1] = f2bf(f2.y); v1[2] = f2bf(f2.z); v1[3] = f2bf(f2.w);
      v1[4] = f2bf(f3.x); v1[5] = f2bf(f3.y); v1[6] = f2bf(f3.z); v1[7] = f2bf(f3.w);
      char* dst = smem + sr * ROW_BYTES + sq * 32;
      *reinterpret_cast<short8*>(dst) = v0;
      *reinterpret_cast<short8*>(dst + 16) = v1;
    }
#pragma unroll
    for (int i = 0; i < 8; ++i) {
      int c = i * 256 + tid;
      int col = c >> 3;
      int part = c & 7;
      short8 v = *reinterpret_cast<const short8*>(w_t + col * 512 + kk0 + part * 8);
      *reinterpret_cast<short8*>(smem + B_OFF + col * ROW_BYTES + part * 16) = v;
    }
    __syncthreads();
#pragma unroll
    for (int ks = 0; ks < 2; ++ks) {
      short8 af[4], bf[4];
#pragma unroll
      for (int rg = 0; rg < 4; ++rg)
        af[rg] = *reinterpret_cast<const short8*>(
            smem + (rg * 16 + lo) * ROW_BYTES + ks * 64 + hi * 16);
#pragma unroll
      for (int cg = 0; cg < 4; ++cg)
        bf[cg] = *reinterpret_cast<const short8*>(
            smem + B_OFF + (w * 64 + cg * 16 + lo) * ROW_BYTES + ks * 64 + hi * 16);
#pragma unroll
      for (int rg = 0; rg < 4; ++rg)
#pragma unroll
        for (int cg = 0; cg < 4; ++cg)
          acc[rg][cg] = __builtin_amdgcn_mfma_f32_16x16x32_bf16(
              af[rg], bf[cg], acc[rg][cg], 0, 0, 0);
    }
    __syncthreads();
  }

  float* U = reinterpret_cast<float*>(smem + B_OFF);
  float* sp = reinterpret_cast<float*>(smem);

  if (w >= 2) {
#pragma unroll
    for (int cg = 0; cg < 4; ++cg) {
      int a = (w - 2) * 64 + cg * 16 + lo;
      float bb = b2[a];
      float wsc = w_score[a];
#pragma unroll
      for (int rg = 0; rg < 4; ++rg)
#pragma unroll
        for (int j = 0; j < 4; ++j) {
          float v = acc[rg][cg][j] + bb;
          float sg = 1.f / (1.f + __expf(-v));
          U[(rg * 16 + hi * 4 + j) * 132 + a] = sg * wsc;
        }
    }
  }
  __syncthreads();
  if (w < 2) {
#pragma unroll
    for (int rg = 0; rg < 4; ++rg) {
      float sacc[4] = {0.f, 0.f, 0.f, 0.f};
#pragma unroll
      for (int cg = 0; cg < 4; ++cg) {
        int a = w * 64 + cg * 16 + lo;
        float bb = b1[a];
#pragma unroll
        for (int j = 0; j < 4; ++j) {
          float v = acc[rg][cg][j] + bb;
          float e2 = __expf(2.f * v);
          float th = 1.f - 2.f / (e2 + 1.f);
          sacc[j] += th * U[(rg * 16 + hi * 4 + j) * 132 + a];
        }
      }
#pragma unroll
      for (int j = 0; j < 4; ++j) {
        float v = sacc[j];
        v += __shfl_xor(v, 1); v += __shfl_xor(v, 2);
        v += __shfl_xor(v, 4); v += __shfl_xor(v, 8);
        if (lo == 0) sp[(rg * 16 + hi * 4 + j) * 2 + w] = v;
      }
    }
  }
  __syncthreads();
  if (tid < 64) score[row0 + tid] = sp[tid * 2] + sp[tid * 2 + 1] + b_score[0];
}

__global__ __launch_bounds__(256) void pool_mlp(
    const float* __restrict__ x, const int* __restrict__ idx,
    const float* __restrict__ score,
    const float* __restrict__ w_m1, const float* __restrict__ b_m1,
    const float* __restrict__ w_m2, const float* __restrict__ b_m2,
    float* __restrict__ out) {
  const int s = blockIdx.x;
  const int tid = threadIdx.x;
  const int start = (s == 0) ? 0 : idx[s - 1];
  const int end = idx[s];

  __shared__ float red[4];
  __shared__ float wgt[1024];
  __shared__ float pooled[512];
  __shared__ float hpart[4][64];

  float m = -INFINITY;
  for (int i = start + tid; i < end; i += 256) m = fmaxf(m, score[i]);
#pragma unroll
  for (int off = 1; off < 64; off <<= 1) m = fmaxf(m, __shfl_xor(m, off));
  if ((tid & 63) == 0) red[tid >> 6] = m;
  __syncthreads();
  m = fmaxf(fmaxf(red[0], red[1]), fmaxf(red[2], red[3]));
  __syncthreads();

  float dsum = 0.f;
  for (int i = start + tid; i < end; i += 256) dsum += __expf(score[i] - m);
#pragma unroll
  for (int off = 1; off < 64; off <<= 1) dsum += __shfl_xor(dsum, off);
  if ((tid & 63) == 0) red[tid >> 6] = dsum;
  __syncthreads();
  dsum = red[0] + red[1] + red[2] + red[3];
  const float inv_d = (end > start) ? 1.f / dsum : 0.f;

  float acc0 = 0.f, acc1 = 0.f;
  const int c0 = tid * 2;
  for (int base = start; base < end; base += 1024) {
    const int cnt = min(1024, end - base);
    __syncthreads();
    for (int i = tid; i < cnt; i += 256)
      wgt[i] = __expf(score[base + i] - m) * inv_d;
    __syncthreads();
    const float* xp = x + (size_t)base * C_DIM + c0;
#pragma unroll 8
    for (int i = 0; i < cnt; ++i) {
      float wv = wgt[i];
      float2 xv = *reinterpret_cast<const float2*>(xp + (size_t)i * C_DIM);
      acc0 = fmaf(wv, xv.x, acc0);
      acc1 = fmaf(wv, xv.y, acc1);
    }
  }
  pooled[c0] = acc0;
  pooled[c0 + 1] = acc1;
  __syncthreads();

  const int o = tid & 63, part = tid >> 6;
  float hs = 0.f;
#pragma unroll 8
  for (int c = part * 128; c < part * 128 + 128; ++c)
    hs = fmaf(pooled[c], w_m1[c * 64 + o], hs);
  hpart[part][o] = hs;
  __syncthreads();
  if (tid < 64) {
    float hv = fmaxf(hpart[0][tid] + hpart[1][tid] + hpart[2][tid] + hpart[3][tid]
                     + b_m1[tid], 0.f);
    float pr = hv * w_m2[tid];
#pragma unroll
    for (int off = 1; off < 64; off <<= 1) pr += __shfl_xor(pr, off);
    if (tid == 0) out[s] = fmaxf(pr + b_m2[0], 0.f);
  }
}

extern "C" void kernel_launch(void* const* d_in, const int* in_sizes, int n_in,
                              void* d_out, int out_size, void* d_ws, size_t ws_size,
                              hipStream_t stream) {
  const float* x       = (const float*)d_in[0];
  const int*   idx_raw = (const int*)d_in[1];
  const float* w1      = (const float*)d_in[2];
  const float* b1      = (const float*)d_in[3];
  const float* w2      = (const float*)d_in[4];
  const float* b2      = (const float*)d_in[5];
  const float* w_score = (const float*)d_in[6];
  const float* b_score = (const float*)d_in[7];
  const float* w_m1    = (const float*)d_in[8];
  const float* b_m1    = (const float*)d_in[9];
  const float* w_m2    = (const float*)d_in[10];
  const float* b_m2    = (const float*)d_in[11];
  float* out = (float*)d_out;

  const int N = in_sizes[0] / C_DIM;   // 262144
  const int S = in_sizes[1];           // 1024

  // ws layout (fused): w_t | idx32 | part_m | part_d | part_acc
  char* wsp = (char*)d_ws;
  short* w_t = (short*)wsp;                       // 512 KB
  size_t off = (size_t)256 * 512 * 2;
  int* idx32 = (int*)(wsp + off);  off += (size_t)S * 4;
  off = (off + 15) & ~(size_t)15;
  float* part_m = (float*)(wsp + off);  off += (size_t)S * PARTS * 4;
  float* part_d = (float*)(wsp + off);  off += (size_t)S * PARTS * 4;
  float* part_acc = (float*)(wsp + off);
  const size_t fused_need = off + (size_t)S * PARTS * C_DIM * 4;

  prep<<<512, 256, 0, stream>>>(w1, w2, w_t, idx_raw, idx32, S);

  if (ws_size >= fused_need) {
    seg_part<<<S * PARTS, 256, 0, stream>>>(x, w_t, b1, b2, w_score, b_score,
                                            idx32, part_m, part_d, part_acc);
    merge_mlp<<<S, 256, 0, stream>>>(part_m, part_d, part_acc,
                                     w_m1, b_m1, w_m2, b_m2, out);
  } else {
    // fallback: two-pass (needs w_t | idx32 | score)
    float* score = (float*)(wsp + ((size_t)256 * 512 * 2 + (size_t)S * 4 + 15 &
                                   ~(size_t)15));
    score_kernel<<<N / 64, 256, 0, stream>>>(x, w_t, b1, b2, w_score, b_score,
                                             score);
    pool_mlp<<<S, 256, 0, stream>>>(x, idx32, score, w_m1, b_m1, w_m2, b_m2, out);
  }
}

// Round 6
// 795.334 us; speedup vs baseline: 1.7038x; 1.7038x over previous
//
#include <hip/hip_runtime.h>

typedef __attribute__((ext_vector_type(8))) short short8;
typedef __attribute__((ext_vector_type(4))) float f32x4;

#define C_DIM 512
#define KSTEP 64
#define ROW_BYTES 144            // 64 bf16 = 128B + 16B pad (2-way max bank aliasing)
#define B_OFF 9216               // A region: 64 * 144
#define GEMM_BYTES 46080         // 9216 + 256*144

// round-to-nearest-even fp32 -> bf16 bits (no NaN in this workload)
__device__ __forceinline__ short f2bf(float f) {
  unsigned u = __float_as_uint(f);
  unsigned r = (u + 0x7fff + ((u >> 16) & 1)) >> 16;
  return (short)r;
}

// prep: w_t[a][k] = bf16(w1|w2 [k][a]); idx -> int32; tile_s0[t] = first seg
// with end > 64*t (searchsorted side=right). int64-vs-int32 idx detection:
// values in [1, N], N < 2^31, so int64 input has odd 32-bit words == 0.
__global__ __launch_bounds__(256) void prep(const float* __restrict__ w1,
                                            const float* __restrict__ w2,
                                            short* __restrict__ w_t,
                                            const int* __restrict__ idx_raw,
                                            int* __restrict__ idx32,
                                            int* __restrict__ tile_s0,
                                            int S, int NT) {
  int t = blockIdx.x * 256 + threadIdx.x;   // 131072 total
  int a = t >> 9;
  int k = t & 511;
  float v = (a < 128) ? w1[k * 128 + a] : w2[k * 128 + (a - 128)];
  w_t[a * 512 + k] = f2bf(v);
  bool is64 = (idx_raw[1] == 0) && (idx_raw[3] == 0);
  if (t < S) idx32[t] = is64 ? idx_raw[2 * t] : idx_raw[t];
  if (t < NT) {
    int row0 = t << 6;
    int lo = 0, hi = S;
    while (lo < hi) {
      int mid = (lo + hi) >> 1;
      int vv = is64 ? idx_raw[2 * mid] : idx_raw[mid];
      if (vv > row0) hi = mid; else lo = mid + 1;
    }
    tile_s0[t] = lo;
  }
}

// One block per 64-row tile: bf16 MFMA GEMM -> gated scores -> per-piece
// (segment-intersection) softmax partials (m, d, sum e*x) written to slot s+t.
// Slot injectivity: within tile t slots are contiguous {s+t}; tile t+1's min
// slot is (tile_s0[t+1]) + t+1 > (last s of tile t) + t. No collisions.
__global__ __launch_bounds__(256, 3) void tile_kernel(
    const float* __restrict__ x, const short* __restrict__ w_t,
    const float* __restrict__ b1, const float* __restrict__ b2,
    const float* __restrict__ w_score, const float* __restrict__ b_score,
    const int* __restrict__ idx32, const int* __restrict__ tile_s0,
    float* __restrict__ piece_m, float* __restrict__ piece_d,
    float* __restrict__ piece_acc, int N, int S) {
  __shared__ __align__(16) char smem[GEMM_BYTES];
  __shared__ float scores_sh[64];
  __shared__ float wexp[64];

  const int t = blockIdx.x;
  const int row0 = t << 6;
  const int tid = threadIdx.x;
  const int w = tid >> 6;
  const int lane = tid & 63;
  const int lo = lane & 15;
  const int hi = lane >> 4;
  const int sr = tid >> 2;         // A-staging row 0..63
  const int sq = tid & 3;          // 16-float chunk
  const int rend = min(row0 + 64, N);

  f32x4 acc[4][4];
#pragma unroll
  for (int i = 0; i < 4; ++i)
#pragma unroll
    for (int j = 0; j < 4; ++j) acc[i][j] = (f32x4)0.f;

  for (int st = 0; st < 8; ++st) {
    const int kk0 = st * KSTEP;
    // issue ALL global loads first (A: 4 float4, B: 8 short8), then convert+write
    float4 fa0, fa1, fa2, fa3;
    const bool aok = (row0 + sr < N);
    if (aok) {
      const float4* srcA = reinterpret_cast<const float4*>(
          x + (size_t)(row0 + sr) * C_DIM + kk0 + sq * 16);
      fa0 = srcA[0]; fa1 = srcA[1]; fa2 = srcA[2]; fa3 = srcA[3];
    } else {
      fa0 = fa1 = fa2 = fa3 = make_float4(0.f, 0.f, 0.f, 0.f);
    }
    short8 vb[8];
#pragma unroll
    for (int i = 0; i < 8; ++i) {
      int c = i * 256 + tid;
      int col = c >> 3;
      int part = c & 7;
      vb[i] = *reinterpret_cast<const short8*>(w_t + col * 512 + kk0 + part * 8);
    }
    {
      short8 v0, v1;
      v0[0] = f2bf(fa0.x); v0[1] = f2bf(fa0.y); v0[2] = f2bf(fa0.z); v0[3] = f2bf(fa0.w);
      v0[4] = f2bf(fa1.x); v0[5] = f2bf(fa1.y); v0[6] = f2bf(fa1.z); v0[7] = f2bf(fa1.w);
      v1[0] = f2bf(fa2.x); v1[1] = f2bf(fa2.y); v1[2] = f2bf(fa2.z); v1[3] = f2bf(fa2.w);
      v1[4] = f2bf(fa3.x); v1[5] = f2bf(fa3.y); v1[6] = f2bf(fa3.z); v1[7] = f2bf(fa3.w);
      char* dst = smem + sr * ROW_BYTES + sq * 32;
      *reinterpret_cast<short8*>(dst) = v0;
      *reinterpret_cast<short8*>(dst + 16) = v1;
    }
#pragma unroll
    for (int i = 0; i < 8; ++i) {
      int c = i * 256 + tid;
      int col = c >> 3;
      int part = c & 7;
      *reinterpret_cast<short8*>(smem + B_OFF + col * ROW_BYTES + part * 16) = vb[i];
    }
    __syncthreads();
#pragma unroll
    for (int ks = 0; ks < 2; ++ks) {
      short8 af[4], bf[4];
#pragma unroll
      for (int rg = 0; rg < 4; ++rg)
        af[rg] = *reinterpret_cast<const short8*>(
            smem + (rg * 16 + lo) * ROW_BYTES + ks * 64 + hi * 16);
#pragma unroll
      for (int cg = 0; cg < 4; ++cg)
        bf[cg] = *reinterpret_cast<const short8*>(
            smem + B_OFF + (w * 64 + cg * 16 + lo) * ROW_BYTES + ks * 64 + hi * 16);
#pragma unroll
      for (int rg = 0; rg < 4; ++rg)
#pragma unroll
        for (int cg = 0; cg < 4; ++cg)
          acc[rg][cg] = __builtin_amdgcn_mfma_f32_16x16x32_bf16(
              af[rg], bf[cg], acc[rg][cg], 0, 0, 0);
    }
    __syncthreads();
  }

  // epilogue: score_r = sum_a tanh(v_a+b1)*sigmoid(u_a+b2)*w_score[a] + b_score
  // C/D layout (verified m89): col = lane&15, row = (lane>>4)*4 + j
  float* U = reinterpret_cast<float*>(smem + B_OFF);  // [64][132] sig(u)*wsc
  float* sp = reinterpret_cast<float*>(smem);         // [64][2] partial sums

  if (w >= 2) {   // u-half (GEMM cols 128..255)
#pragma unroll
    for (int cg = 0; cg < 4; ++cg) {
      int a = (w - 2) * 64 + cg * 16 + lo;
      float bb = b2[a];
      float wsc = w_score[a];
#pragma unroll
      for (int rg = 0; rg < 4; ++rg)
#pragma unroll
        for (int j = 0; j < 4; ++j) {
          float v = acc[rg][cg][j] + bb;
          float sg = 1.f / (1.f + __expf(-v));
          U[(rg * 16 + hi * 4 + j) * 132 + a] = sg * wsc;
        }
    }
  }
  __syncthreads();
  if (w < 2) {    // v-half (GEMM cols 0..127)
#pragma unroll
    for (int rg = 0; rg < 4; ++rg) {
      float sacc[4] = {0.f, 0.f, 0.f, 0.f};
#pragma unroll
      for (int cg = 0; cg < 4; ++cg) {
        int a = w * 64 + cg * 16 + lo;
        float bb = b1[a];
#pragma unroll
        for (int j = 0; j < 4; ++j) {
          float v = acc[rg][cg][j] + bb;
          float e2 = __expf(2.f * v);
          float th = 1.f - 2.f / (e2 + 1.f);
          sacc[j] += th * U[(rg * 16 + hi * 4 + j) * 132 + a];
        }
      }
#pragma unroll
      for (int j = 0; j < 4; ++j) {
        float v = sacc[j];
        v += __shfl_xor(v, 1); v += __shfl_xor(v, 2);
        v += __shfl_xor(v, 4); v += __shfl_xor(v, 8);
        if (lo == 0) sp[(rg * 16 + hi * 4 + j) * 2 + w] = v;
      }
    }
  }
  __syncthreads();
  if (tid < 64) scores_sh[tid] = sp[tid * 2] + sp[tid * 2 + 1] + b_score[0];
  __syncthreads();

  // piece sweep: split [row0, rend) at segment boundaries; per piece write
  // m, d = sum exp(s-m), acc = sum exp(s-m)*x to slot (s + t).
  int s = tile_s0[t];
  int rlo = row0;
  const int c0 = tid * 2;
  while (rlo < rend && s < S) {
    const int seg_end = idx32[s];
    const int rhi = min(seg_end, rend);
    const int l0 = rlo - row0;
    const int cnt = rhi - rlo;
    const int slot = s + t;
    if (tid < 64) {
      float sv = (tid < cnt) ? scores_sh[l0 + tid] : -INFINITY;
      float mv = sv;
#pragma unroll
      for (int off = 1; off < 64; off <<= 1) mv = fmaxf(mv, __shfl_xor(mv, off));
      float e = (tid < cnt) ? __expf(sv - mv) : 0.f;
      wexp[tid] = e;
      float dv = e;
#pragma unroll
      for (int off = 1; off < 64; off <<= 1) dv += __shfl_xor(dv, off);
      if (tid == 0) { piece_m[slot] = mv; piece_d[slot] = dv; }
    }
    __syncthreads();
    float a0 = 0.f, a1 = 0.f;
    const float* xp = x + (size_t)rlo * C_DIM + c0;
#pragma unroll 8
    for (int j = 0; j < cnt; ++j) {
      float wv = wexp[j];
      float2 xv = *reinterpret_cast<const float2*>(xp + (size_t)j * C_DIM);
      a0 = fmaf(wv, xv.x, a0);
      a1 = fmaf(wv, xv.y, a1);
    }
    piece_acc[(size_t)slot * C_DIM + c0] = a0;
    piece_acc[(size_t)slot * C_DIM + c0 + 1] = a1;
    __syncthreads();   // wexp reused next piece
    rlo = rhi;
    ++s;
  }
}

// One block per segment: merge pieces (slots s+t, t in [start/64, (end-1)/64]),
// then MLP head.
__global__ __launch_bounds__(256) void merge_mlp(
    const int* __restrict__ idx32,
    const float* __restrict__ piece_m, const float* __restrict__ piece_d,
    const float* __restrict__ piece_acc,
    const float* __restrict__ w_m1, const float* __restrict__ b_m1,
    const float* __restrict__ w_m2, const float* __restrict__ b_m2,
    float* __restrict__ out) {
  const int s = blockIdx.x;
  const int tid = threadIdx.x;
  const int start = (s == 0) ? 0 : idx32[s - 1];
  const int end = idx32[s];
  __shared__ float pooled[512];
  __shared__ float hpart[4][64];

  const int c0 = tid * 2;
  float a0 = 0.f, a1 = 0.f;
  float D = 0.f;
  if (end > start) {
    const int t0 = start >> 6;
    const int t1 = (end - 1) >> 6;
    float M = -INFINITY;
    for (int t = t0; t <= t1; ++t) M = fmaxf(M, piece_m[s + t]);
    for (int t = t0; t <= t1; ++t) {
      const float wp = __expf(piece_m[s + t] - M);
      D += piece_d[s + t] * wp;
      const float* pa = piece_acc + (size_t)(s + t) * C_DIM;
      a0 = fmaf(pa[c0], wp, a0);
      a1 = fmaf(pa[c0 + 1], wp, a1);
    }
  }
  const float inv = (D > 0.f) ? 1.f / D : 0.f;
  pooled[c0] = a0 * inv;
  pooled[c0 + 1] = a1 * inv;
  __syncthreads();

  // MLP: h = relu(pooled @ w_m1 + b_m1); out = relu(h @ w_m2 + b_m2)
  const int o = tid & 63, part = tid >> 6;
  float hs = 0.f;
#pragma unroll 8
  for (int c = part * 128; c < part * 128 + 128; ++c)
    hs = fmaf(pooled[c], w_m1[c * 64 + o], hs);
  hpart[part][o] = hs;
  __syncthreads();
  if (tid < 64) {
    float hv = fmaxf(hpart[0][tid] + hpart[1][tid] + hpart[2][tid] + hpart[3][tid]
                     + b_m1[tid], 0.f);
    float pr = hv * w_m2[tid];
#pragma unroll
    for (int off = 1; off < 64; off <<= 1) pr += __shfl_xor(pr, off);
    if (tid == 0) out[s] = fmaxf(pr + b_m2[0], 0.f);
  }
}

extern "C" void kernel_launch(void* const* d_in, const int* in_sizes, int n_in,
                              void* d_out, int out_size, void* d_ws, size_t ws_size,
                              hipStream_t stream) {
  const float* x       = (const float*)d_in[0];
  const int*   idx_raw = (const int*)d_in[1];
  const float* w1      = (const float*)d_in[2];
  const float* b1      = (const float*)d_in[3];
  const float* w2      = (const float*)d_in[4];
  const float* b2      = (const float*)d_in[5];
  const float* w_score = (const float*)d_in[6];
  const float* b_score = (const float*)d_in[7];
  const float* w_m1    = (const float*)d_in[8];
  const float* b_m1    = (const float*)d_in[9];
  const float* w_m2    = (const float*)d_in[10];
  const float* b_m2    = (const float*)d_in[11];
  float* out = (float*)d_out;

  const int N = in_sizes[0] / C_DIM;   // 262144
  const int S = in_sizes[1];           // 1024
  const int NT = (N + 63) >> 6;        // 4096 tiles
  const int SLOTS = NT + S;            // max slot id = (S-1)+(NT-1) < NT+S

  // ws layout: w_t | idx32 | tile_s0 | piece_m | piece_d | piece_acc
  char* wsp = (char*)d_ws;
  short* w_t = (short*)wsp;
  size_t off = (size_t)256 * 512 * 2;                       // 262144
  int* idx32 = (int*)(wsp + off);    off += (size_t)S * 4;
  off = (off + 15) & ~(size_t)15;
  int* tile_s0 = (int*)(wsp + off);  off += (size_t)NT * 4;
  off = (off + 15) & ~(size_t)15;
  float* piece_m = (float*)(wsp + off);  off += (size_t)SLOTS * 4;
  off = (off + 15) & ~(size_t)15;
  float* piece_d = (float*)(wsp + off);  off += (size_t)SLOTS * 4;
  off = (off + 15) & ~(size_t)15;
  float* piece_acc = (float*)(wsp + off);
  const size_t need = off + (size_t)SLOTS * C_DIM * 4;      // ~10.3 MB
  if (ws_size < need) return;   // deterministic no-op guard (never expected to hit)

  prep<<<512, 256, 0, stream>>>(w1, w2, w_t, idx_raw, idx32, tile_s0, S, NT);
  tile_kernel<<<NT, 256, 0, stream>>>(x, w_t, b1, b2, w_score, b_score,
                                      idx32, tile_s0, piece_m, piece_d,
                                      piece_acc, N, S);
  merge_mlp<<<S, 256, 0, stream>>>(idx32, piece_m, piece_d, piece_acc,
                                   w_m1, b_m1, w_m2, b_m2, out);
}